// Round 1
// baseline (776.027 us; speedup 1.0000x reference)
//
#include <hip/hip_runtime.h>
#include <cstdint>

#define NTHREADS 512
#define L_SEQ 2048
#define D_DIM 1024
#define BQ 64
#define BK 32
#define NKT (L_SEQ / BK)   // 64 key tiles

// ---- fallback (original) kernel LDS layout ----
#define KST 1032
#define VST 34
#define SST 36
#define PST 40
#define K_OFF 0
#define K_BYTES (BK * KST * 2)
#define V_OFF (K_OFF + K_BYTES)
#define V_BYTES (D_DIM * VST * 2)
#define S_OFF (V_OFF + V_BYTES)
#define S_BYTES (BQ * SST * 4)
#define P_OFF (S_OFF + S_BYTES)
#define P_BYTES (BQ * PST * 2)
#define M_OFF (P_OFF + P_BYTES)
#define LDS_TOTAL (M_OFF + BQ * 4 * 3 + 16)

typedef unsigned int u32;
typedef __bf16 bf16x8 __attribute__((ext_vector_type(8)));
typedef float f32x4 __attribute__((ext_vector_type(4)));

__device__ __forceinline__ f32x4 mfma16(int4 a, int4 b, f32x4 c) {
  return __builtin_amdgcn_mfma_f32_16x16x32_bf16(
      __builtin_bit_cast(bf16x8, a), __builtin_bit_cast(bf16x8, b), c, 0, 0, 0);
}

// pack two fp32 -> bf16x2 (same rounding as previous verified kernel)
__device__ __forceinline__ u32 pk2(float a, float b) {
  u32 ua = __float_as_uint(a) + 0x8000u;
  u32 ub = __float_as_uint(b) + 0x8000u;
  return (ua >> 16) | (ub & 0xffff0000u);
}

#define SFIX 4096.0f

// ================= prologue: K -> bf16 (same layout), V -> bf16 tile-transposed =================
// Vt layout: [b][kt][d][32 keys] bf16, each tile a contiguous 64KB chunk.
#define VP 1026                      // fp32 LDS row pad (2-way bank alias = free)
#define CVT_LDS (32 * VP * 4)        // 131328 B

__global__ __launch_bounds__(256)
void cvt_kv(const float* __restrict__ Kg, const float* __restrict__ Vg,
            unsigned short* __restrict__ Kb16, unsigned short* __restrict__ Vt) {
  extern __shared__ float vls[];     // [32][VP]
  const int tid = threadIdx.x;
  const int kt = blockIdx.x;
  const int b = blockIdx.y;
  const size_t inbase = ((size_t)b * L_SEQ + (size_t)kt * BK) * D_DIM;

  // K tile convert: 32x1024 fp32 -> bf16, flat coalesced
  {
    const float4* Ks = (const float4*)(Kg + inbase);
    uint2* Ko = (uint2*)(Kb16 + inbase);
#pragma unroll 4
    for (int i = 0; i < 32; ++i) {
      int u = i * 256 + tid;
      float4 x = Ks[u];
      Ko[u] = make_uint2(pk2(x.x, x.y), pk2(x.z, x.w));
    }
  }
  // V tile -> LDS (fp32, coalesced reads)
  {
    const float4* Vs = (const float4*)(Vg + inbase);
#pragma unroll 4
    for (int i = 0; i < 32; ++i) {
      int u = i * 256 + tid;
      float4 x = Vs[u];
      int row = u >> 8;
      int c = (u & 255) * 4;
      float* p = &vls[row * VP + c];
      p[0] = x.x; p[1] = x.y; p[2] = x.z; p[3] = x.w;
    }
  }
  __syncthreads();
  // transposed write: Vt[d][key] bf16, 16B stores, fully coalesced
  {
    int4* Vo = (int4*)(Vt + ((size_t)b * NKT + kt) * (size_t)(D_DIM * BK));
#pragma unroll 4
    for (int i = 0; i < 16; ++i) {
      int o4 = i * 256 + tid;          // int4 index within tile (4096 total)
      int d = o4 >> 2;                 // d-row (4 int4 per row)
      int kp0 = (o4 & 3) * 4;          // key-pair start
      u32 w0, w1, w2, w3;
      w0 = pk2(vls[(2 * (kp0 + 0)) * VP + d], vls[(2 * (kp0 + 0) + 1) * VP + d]);
      w1 = pk2(vls[(2 * (kp0 + 1)) * VP + d], vls[(2 * (kp0 + 1) + 1) * VP + d]);
      w2 = pk2(vls[(2 * (kp0 + 2)) * VP + d], vls[(2 * (kp0 + 2) + 1) * VP + d]);
      w3 = pk2(vls[(2 * (kp0 + 3)) * VP + d], vls[(2 * (kp0 + 3) + 1) * VP + d]);
      Vo[o4] = make_int4((int)w0, (int)w1, (int)w2, (int)w3);
    }
  }
}

// ================= main kernel: no K/V LDS staging, direct bf16 fragment loads =================
__global__ __attribute__((amdgpu_waves_per_eu(2, 2))) __launch_bounds__(NTHREADS)
void fa_fwd_pre(const float* __restrict__ Qg, const unsigned short* __restrict__ Kb16,
                const unsigned short* __restrict__ Vt, float* __restrict__ Og, int B) {
  __shared__ int Ssh[BQ * SST];                 // fixed-point partial scores
  __shared__ unsigned short Psh[BQ * PST];      // bf16 probs
  __shared__ float msh[BQ], lsh[BQ], ash[BQ];   // running max / denom / alpha
  __shared__ int fsh[2][4];                     // double-buffered rescale flags

  const int tid = threadIdx.x;
  const int lane = tid & 63;
  const int wave = tid >> 6;         // d-slice owner: cols [wave*128, wave*128+128)
  const int r = lane & 15;
  const int quad = lane >> 4;

  // flattened heavy-first mapping (greedy LPT across CUs)
  const int f = (int)blockIdx.y * (int)gridDim.x + (int)blockIdx.x;
  const int b = f % B;
  const int qtile = (int)gridDim.x - 1 - (f / B);
  const int q0 = qtile * BQ;
  const size_t base = (size_t)b * L_SEQ * D_DIM;
  const float* Qb = Qg + base;
  const unsigned short* Kbb = Kb16 + base;
  const unsigned short* Vtb = Vt + (size_t)b * NKT * (size_t)(D_DIM * BK);
  float* Ob = Og + base;

  // ---- Q fragments, bf16, persistent: A[m=lane&15][k=quad*8+j] over this wave's d-slice ----
  int4 qf[4][4];
#pragma unroll
  for (int m = 0; m < 4; ++m)
#pragma unroll
    for (int ks = 0; ks < 4; ++ks) {
      const float* src = Qb + (size_t)(q0 + m * 16 + r) * D_DIM + wave * 128 + ks * 32 + quad * 8;
      float4 x = *(const float4*)src;
      float4 y = *(const float4*)(src + 4);
      qf[m][ks] = make_int4((int)pk2(x.x, x.y), (int)pk2(x.z, x.w),
                            (int)pk2(y.x, y.y), (int)pk2(y.z, y.w));
    }

  f32x4 o[4][8];
  const f32x4 fzero = {0.f, 0.f, 0.f, 0.f};
#pragma unroll
  for (int m = 0; m < 4; ++m)
#pragma unroll
    for (int n = 0; n < 8; ++n) o[m][n] = fzero;

  if (tid < BQ) { msh[tid] = -3.0e38f; lsh[tid] = 0.f; }
  if (tid < 8) fsh[tid >> 2][tid & 3] = 0;
  {  // zero score buffer once; thereafter softmax re-zeros its own int4
    int q = tid >> 3, k4 = (tid & 7) * 4;
    *(int4*)&Ssh[q * SST + k4] = make_int4(0, 0, 0, 0);
  }
  __syncthreads();

  const int nkt = q0 / BK + 2;                 // causal tile skip
  const float SC = 0.04508422002778011f;       // log2(e) / sqrt(1024)
  const float SCI = SC / SFIX;

  for (int kt = 0; kt < nkt; ++kt) {
    const int cur = kt & 1;

    // ---- QK^T: direct global bf16 K fragments, reduce via LDS int atomics ----
#pragma unroll
    for (int nb = 0; nb < 2; ++nb) {
      f32x4 sp[4];
#pragma unroll
      for (int m = 0; m < 4; ++m) sp[m] = fzero;
#pragma unroll
      for (int ks = 0; ks < 4; ++ks) {
        int4 kb = *(const int4*)(Kbb + (size_t)(kt * BK + nb * 16 + r) * D_DIM +
                                 wave * 128 + ks * 32 + quad * 8);
#pragma unroll
        for (int m = 0; m < 4; ++m) sp[m] = mfma16(qf[m][ks], kb, sp[m]);
      }
#pragma unroll
      for (int m = 0; m < 4; ++m)
#pragma unroll
        for (int i = 0; i < 4; ++i) {
          int v = __float2int_rn(sp[m][i] * SFIX);
          atomicAdd(&Ssh[(m * 16 + quad * 4 + i) * SST + nb * 16 + r], v);
        }
    }
    __syncthreads();  // (1) S complete; prev-tile P/ash consumers also done

    // ---- online softmax: 8 threads per row; re-zero own S int4 for next tile ----
    {
      int q = tid >> 3, kk = (tid & 7) * 4;
      int4 sv = *(int4*)&Ssh[q * SST + kk];
      *(int4*)&Ssh[q * SST + kk] = make_int4(0, 0, 0, 0);
      int qglob = q0 + q, kglob = kt * BK + kk;
      float e0 = (kglob <= qglob) ? (float)sv.x * SCI : -1e30f;
      float e1 = (kglob + 1 <= qglob) ? (float)sv.y * SCI : -1e30f;
      float e2 = (kglob + 2 <= qglob) ? (float)sv.z * SCI : -1e30f;
      float e3 = (kglob + 3 <= qglob) ? (float)sv.w * SCI : -1e30f;
      float mx = fmaxf(fmaxf(e0, e1), fmaxf(e2, e3));
      mx = fmaxf(mx, __shfl_xor(mx, 1));
      mx = fmaxf(mx, __shfl_xor(mx, 2));
      mx = fmaxf(mx, __shfl_xor(mx, 4));
      float mprev = msh[q], lprev = lsh[q];
      float mnew = fmaxf(mprev, mx);
      float alpha = exp2f(mprev - mnew);
      float p0 = exp2f(e0 - mnew), p1 = exp2f(e1 - mnew);
      float p2 = exp2f(e2 - mnew), p3 = exp2f(e3 - mnew);
      float sum = (p0 + p1) + (p2 + p3);
      sum += __shfl_xor(sum, 1);
      sum += __shfl_xor(sum, 2);
      sum += __shfl_xor(sum, 4);
      *(uint2*)&Psh[q * PST + kk] = make_uint2(pk2(p0, p1), pk2(p2, p3));
      if ((tid & 7) == 0) {
        msh[q] = mnew;
        lsh[q] = lprev * alpha + sum;
        ash[q] = alpha;
        if (alpha != 1.0f) fsh[cur][q >> 4] = 1;  // same-value racy store: fine
      }
      if (tid < 4) fsh[cur ^ 1][tid] = 0;          // reset next tile's flags
    }
    __syncthreads();  // (2) P/alpha/flags ready

    // ---- conditional O rescale + PV with direct global V fragments ----
    {
#pragma unroll
      for (int m = 0; m < 4; ++m) {
        if (fsh[cur][m]) {  // wave-uniform; rarely taken after max saturates
          float a0 = ash[m * 16 + quad * 4 + 0];
          float a1 = ash[m * 16 + quad * 4 + 1];
          float a2 = ash[m * 16 + quad * 4 + 2];
          float a3 = ash[m * 16 + quad * 4 + 3];
#pragma unroll
          for (int n = 0; n < 8; ++n) {
            o[m][n][0] *= a0; o[m][n][1] *= a1; o[m][n][2] *= a2; o[m][n][3] *= a3;
          }
        }
      }
      int4 pf[4];
#pragma unroll
      for (int m = 0; m < 4; ++m)
        pf[m] = *(int4*)&Psh[(m * 16 + r) * PST + quad * 8];
      const unsigned short* Vtt = Vtb + (size_t)kt * (D_DIM * BK);
#pragma unroll
      for (int n = 0; n < 8; ++n) {
        // 16 consecutive 64B d-rows -> each wave load is 1KB fully contiguous
        int4 vb = *(const int4*)(Vtt + (wave * 128 + n * 16 + r) * BK + quad * 8);
#pragma unroll
        for (int m = 0; m < 4; ++m) o[m][n] = mfma16(pf[m], vb, o[m][n]);
      }
    }
  }

  // ---- epilogue: O / l ----
#pragma unroll
  for (int m = 0; m < 4; ++m) {
    float inv0 = 1.0f / lsh[m * 16 + quad * 4 + 0];
    float inv1 = 1.0f / lsh[m * 16 + quad * 4 + 1];
    float inv2 = 1.0f / lsh[m * 16 + quad * 4 + 2];
    float inv3 = 1.0f / lsh[m * 16 + quad * 4 + 3];
#pragma unroll
    for (int n = 0; n < 8; ++n) {
      size_t row = (size_t)q0 + m * 16 + quad * 4;
      size_t col = (size_t)wave * 128 + n * 16 + r;
      Ob[(row + 0) * D_DIM + col] = o[m][n][0] * inv0;
      Ob[(row + 1) * D_DIM + col] = o[m][n][1] * inv1;
      Ob[(row + 2) * D_DIM + col] = o[m][n][2] * inv2;
      Ob[(row + 3) * D_DIM + col] = o[m][n][3] * inv3;
    }
  }
}

// ================= fallback: previous verified kernel (used if workspace too small) =================
__global__ __attribute__((amdgpu_waves_per_eu(2, 2))) __launch_bounds__(NTHREADS)
void fa_fwd(const float* __restrict__ Qg, const float* __restrict__ Kg,
            const float* __restrict__ Vg, float* __restrict__ Og) {
  extern __shared__ char smem[];
  unsigned short* Ksh = (unsigned short*)(smem + K_OFF);
  unsigned short* Vtsh = (unsigned short*)(smem + V_OFF);
  int* Ssh = (int*)(smem + S_OFF);
  unsigned short* Psh = (unsigned short*)(smem + P_OFF);
  float* msh = (float*)(smem + M_OFF);
  float* lsh = msh + BQ;
  float* ash = lsh + BQ;
  int* fsh = (int*)(ash + BQ);

  const int tid = threadIdx.x;
  const int lane = tid & 63;
  const int wave = tid >> 6;
  const int r = lane & 15;
  const int quad = lane >> 4;

  const int qtile = (int)gridDim.x - 1 - (int)blockIdx.x;
  const int q0 = qtile * BQ;
  const int b = blockIdx.y;
  const size_t base = (size_t)b * L_SEQ * D_DIM;
  const float* Qb = Qg + base;
  const float* Kb = Kg + base;
  const float* Vb = Vg + base;
  float* Ob = Og + base;

  int4 qf[4][4];
#pragma unroll
  for (int m = 0; m < 4; ++m)
#pragma unroll
    for (int ks = 0; ks < 4; ++ks) {
      const float* src = Qb + (size_t)(q0 + m * 16 + r) * D_DIM + wave * 128 + ks * 32 + quad * 8;
      float4 x = *(const float4*)src;
      float4 y = *(const float4*)(src + 4);
      qf[m][ks] = make_int4((int)pk2(x.x, x.y), (int)pk2(x.z, x.w),
                            (int)pk2(y.x, y.y), (int)pk2(y.z, y.w));
    }

  f32x4 o[4][8];
  const f32x4 fzero = {0.f, 0.f, 0.f, 0.f};
#pragma unroll
  for (int m = 0; m < 4; ++m)
#pragma unroll
    for (int n = 0; n < 8; ++n) o[m][n] = fzero;

  if (tid < BQ) { msh[tid] = -3.0e38f; lsh[tid] = 0.f; }

  const int nkt = q0 / BK + 2;
  const float SC = 0.04508422002778011f;
  const float SCI = SC / SFIX;

  for (int kt = 0; kt < nkt; ++kt) {
    __syncthreads();
    {
      const float* Ks = Kb + (size_t)kt * BK * D_DIM;
#pragma unroll 8
      for (int i = 0; i < 16; ++i) {
        int u = i * NTHREADS + tid;
        int key = u >> 8;
        int c = u & 255;
        float4 v = *(const float4*)(Ks + key * D_DIM + c * 4);
        *(uint2*)&Ksh[key * KST + c * 4] = make_uint2(pk2(v.x, v.y), pk2(v.z, v.w));
      }
      const float* Vs = Vb + (size_t)kt * BK * D_DIM;
#pragma unroll 8
      for (int i = 0; i < 32; ++i) {
        int u = i * NTHREADS + tid;
        int kp = u >> 10;
        int d = u & 1023;
        float a = Vs[kp * 2 * D_DIM + d];
        float c2 = Vs[(kp * 2 + 1) * D_DIM + d];
        *(u32*)&Vtsh[d * VST + kp * 2] = pk2(a, c2);
      }
      int q = tid >> 3, k4 = (tid & 7) * 4;
      *(int4*)&Ssh[q * SST + k4] = make_int4(0, 0, 0, 0);
      if (tid < 4) fsh[tid] = 0;
    }
    __syncthreads();

#pragma unroll
    for (int nb = 0; nb < 2; ++nb) {
      f32x4 sp[4];
#pragma unroll
      for (int m = 0; m < 4; ++m) sp[m] = fzero;
#pragma unroll
      for (int ks = 0; ks < 4; ++ks) {
        int dcol = wave * 128 + ks * 32 + quad * 8;
        int4 kb = *(int4*)&Ksh[(nb * 16 + r) * KST + dcol];
#pragma unroll
        for (int m = 0; m < 4; ++m) sp[m] = mfma16(qf[m][ks], kb, sp[m]);
      }
#pragma unroll
      for (int m = 0; m < 4; ++m)
#pragma unroll
        for (int i = 0; i < 4; ++i) {
          int v = __float2int_rn(sp[m][i] * SFIX);
          atomicAdd(&Ssh[(m * 16 + quad * 4 + i) * SST + nb * 16 + r], v);
        }
    }
    __syncthreads();

    {
      int q = tid >> 3, kk = (tid & 7) * 4;
      int4 sv = *(int4*)&Ssh[q * SST + kk];
      int qglob = q0 + q, kglob = kt * BK + kk;
      float e0 = (kglob <= qglob) ? (float)sv.x * SCI : -1e30f;
      float e1 = (kglob + 1 <= qglob) ? (float)sv.y * SCI : -1e30f;
      float e2 = (kglob + 2 <= qglob) ? (float)sv.z * SCI : -1e30f;
      float e3 = (kglob + 3 <= qglob) ? (float)sv.w * SCI : -1e30f;
      float mx = fmaxf(fmaxf(e0, e1), fmaxf(e2, e3));
      mx = fmaxf(mx, __shfl_xor(mx, 1));
      mx = fmaxf(mx, __shfl_xor(mx, 2));
      mx = fmaxf(mx, __shfl_xor(mx, 4));
      float mprev = msh[q], lprev = lsh[q];
      float mnew = fmaxf(mprev, mx);
      float alpha = exp2f(mprev - mnew);
      float p0 = exp2f(e0 - mnew), p1 = exp2f(e1 - mnew);
      float p2 = exp2f(e2 - mnew), p3 = exp2f(e3 - mnew);
      float sum = (p0 + p1) + (p2 + p3);
      sum += __shfl_xor(sum, 1);
      sum += __shfl_xor(sum, 2);
      sum += __shfl_xor(sum, 4);
      *(uint2*)&Psh[q * PST + kk] = make_uint2(pk2(p0, p1), pk2(p2, p3));
      if ((tid & 7) == 0) {
        msh[q] = mnew;
        lsh[q] = lprev * alpha + sum;
        ash[q] = alpha;
        if (alpha != 1.0f) fsh[q >> 4] = 1;
      }
    }
    __syncthreads();

    {
#pragma unroll
      for (int m = 0; m < 4; ++m) {
        if (fsh[m]) {
          float a0 = ash[m * 16 + quad * 4 + 0];
          float a1 = ash[m * 16 + quad * 4 + 1];
          float a2 = ash[m * 16 + quad * 4 + 2];
          float a3 = ash[m * 16 + quad * 4 + 3];
#pragma unroll
          for (int n = 0; n < 8; ++n) {
            o[m][n][0] *= a0; o[m][n][1] *= a1; o[m][n][2] *= a2; o[m][n][3] *= a3;
          }
        }
      }
      int4 pf[4];
#pragma unroll
      for (int m = 0; m < 4; ++m)
        pf[m] = *(int4*)&Psh[(m * 16 + r) * PST + quad * 8];
#pragma unroll
      for (int n = 0; n < 8; ++n) {
        const unsigned short* vp = &Vtsh[(wave * 128 + n * 16 + r) * VST + quad * 8];
        int4 vb = make_int4(*(const u32*)vp, *(const u32*)(vp + 2),
                            *(const u32*)(vp + 4), *(const u32*)(vp + 6));
#pragma unroll
        for (int m = 0; m < 4; ++m) o[m][n] = mfma16(pf[m], vb, o[m][n]);
      }
    }
  }

#pragma unroll
  for (int m = 0; m < 4; ++m) {
    float inv0 = 1.0f / lsh[m * 16 + quad * 4 + 0];
    float inv1 = 1.0f / lsh[m * 16 + quad * 4 + 1];
    float inv2 = 1.0f / lsh[m * 16 + quad * 4 + 2];
    float inv3 = 1.0f / lsh[m * 16 + quad * 4 + 3];
#pragma unroll
    for (int n = 0; n < 8; ++n) {
      size_t row = (size_t)q0 + m * 16 + quad * 4;
      size_t col = (size_t)wave * 128 + n * 16 + r;
      Ob[(row + 0) * D_DIM + col] = o[m][n][0] * inv0;
      Ob[(row + 1) * D_DIM + col] = o[m][n][1] * inv1;
      Ob[(row + 2) * D_DIM + col] = o[m][n][2] * inv2;
      Ob[(row + 3) * D_DIM + col] = o[m][n][3] * inv3;
    }
  }
}

extern "C" void kernel_launch(void* const* d_in, const int* in_sizes, int n_in,
                              void* d_out, int out_size, void* d_ws, size_t ws_size,
                              hipStream_t stream) {
  const float* Q = (const float*)d_in[0];
  const float* K = (const float*)d_in[1];
  const float* V = (const float*)d_in[2];
  float* O = (float*)d_out;
  int B = in_sizes[0] / (L_SEQ * D_DIM);

  size_t need = (size_t)B * L_SEQ * D_DIM * 2ull * 2ull;  // Kb16 + Vt (bf16)
  if (d_ws != nullptr && ws_size >= need) {
    unsigned short* Kb16 = (unsigned short*)d_ws;
    unsigned short* Vt = Kb16 + (size_t)B * L_SEQ * D_DIM;
    hipFuncSetAttribute((const void*)cvt_kv, hipFuncAttributeMaxDynamicSharedMemorySize,
                        CVT_LDS);
    dim3 g1(NKT, B);
    cvt_kv<<<g1, 256, CVT_LDS, stream>>>(K, V, Kb16, Vt);
    dim3 g2(L_SEQ / BQ, B);
    fa_fwd_pre<<<g2, NTHREADS, 0, stream>>>(Q, Kb16, Vt, O, B);
  } else {
    hipFuncSetAttribute((const void*)fa_fwd, hipFuncAttributeMaxDynamicSharedMemorySize,
                        LDS_TOTAL);
    dim3 grid(L_SEQ / BQ, B);
    fa_fwd<<<grid, NTHREADS, LDS_TOTAL, stream>>>(Q, K, V, O);
  }
}

// Round 3
// 694.075 us; speedup vs baseline: 1.1181x; 1.1181x over previous
//
#include <hip/hip_runtime.h>
#include <cstdint>

#define NTHREADS 512
#define L_SEQ 2048
#define D_DIM 1024
#define BQ 64
#define BK 32
#define NKT (L_SEQ / BK)   // 64 key tiles
#define NQT (L_SEQ / BQ)   // 32 query tiles

// ---- fallback (original) kernel LDS layout ----
#define KST 1032
#define VST 34
#define SST 36
#define PST 40
#define K_OFF 0
#define K_BYTES (BK * KST * 2)
#define V_OFF (K_OFF + K_BYTES)
#define V_BYTES (D_DIM * VST * 2)
#define S_OFF (V_OFF + V_BYTES)
#define S_BYTES (BQ * SST * 4)
#define P_OFF (S_OFF + S_BYTES)
#define P_BYTES (BQ * PST * 2)
#define M_OFF (P_OFF + P_BYTES)
#define LDS_TOTAL (M_OFF + BQ * 4 * 3 + 16)

typedef unsigned int u32;
typedef __bf16 bf16x8 __attribute__((ext_vector_type(8)));
typedef float f32x4 __attribute__((ext_vector_type(4)));

// nt-load helper: __builtin_nontemporal_load rejects HIP_vector_type pointers,
// but accepts clang ext_vector_type.
__device__ __forceinline__ f32x4 ntload4(const float* p) {
  return __builtin_nontemporal_load((const f32x4*)p);
}

__device__ __forceinline__ f32x4 mfma16(int4 a, int4 b, f32x4 c) {
  return __builtin_amdgcn_mfma_f32_16x16x32_bf16(
      __builtin_bit_cast(bf16x8, a), __builtin_bit_cast(bf16x8, b), c, 0, 0, 0);
}

// pack two fp32 -> bf16x2 (same rounding as previous verified kernel)
__device__ __forceinline__ u32 pk2(float a, float b) {
  u32 ua = __float_as_uint(a) + 0x8000u;
  u32 ub = __float_as_uint(b) + 0x8000u;
  return (ua >> 16) | (ub & 0xffff0000u);
}

#define SFIX 4096.0f

// ================= prologue: K -> bf16 (same layout), V -> bf16 tile-transposed =================
// Vt layout: [b][kt][d][32 keys] bf16, each tile a contiguous 64KB chunk.
// 33 KB LDS (4 blocks/CU), 512 threads, nt fp32 loads. Numerics identical to before.
#define CVT_PAD 257   // 257 % 32 == 1 -> transpose-gather reads are 2-way (free)

__global__ __launch_bounds__(512)
void cvt_kv(const float* __restrict__ Kg, const float* __restrict__ Vg,
            unsigned short* __restrict__ Kb16, unsigned short* __restrict__ Vt) {
  __shared__ float vls[32 * CVT_PAD];   // 32.9 KB
  const int tid = threadIdx.x;
  const int kt = blockIdx.x;
  const int b = blockIdx.y;
  const size_t inbase = ((size_t)b * L_SEQ + (size_t)kt * BK) * D_DIM;

  // K tile convert: 32x1024 fp32 -> bf16, flat coalesced, nt reads
  {
    const float* Ks = Kg + inbase;
    uint2* Ko = (uint2*)(Kb16 + inbase);
#pragma unroll
    for (int i = 0; i < 16; ++i) {
      f32x4 x = ntload4(Ks + (size_t)(i * 512 + tid) * 4);
      Ko[i * 512 + tid] = make_uint2(pk2(x[0], x[1]), pk2(x[2], x[3]));
    }
  }
  // V transpose in 4 chunks of 256 d-columns
  const float* Vsf = Vg + inbase;
  int4* Vo = (int4*)(Vt + ((size_t)b * NKT + kt) * (size_t)(D_DIM * BK));
  for (int c = 0; c < 4; ++c) {
    __syncthreads();   // previous chunk's readers done
#pragma unroll
    for (int i = 0; i < 4; ++i) {
      int u = i * 512 + tid;           // 0..2047
      int row = u >> 6;                // key 0..31
      int col4 = u & 63;               // float4 within 256-d chunk
      f32x4 x = ntload4(Vsf + (size_t)row * D_DIM + c * 256 + col4 * 4);
      *(f32x4*)&vls[row * CVT_PAD + col4 * 4] = x;
    }
    __syncthreads();
#pragma unroll
    for (int i = 0; i < 2; ++i) {
      int o4 = i * 512 + tid;          // 0..1023
      int d = o4 >> 2;                 // 0..255 (chunk-local)
      int k0 = (o4 & 3) * 8;           // key start for this int4 (8 keys)
      u32 w0 = pk2(vls[(k0 + 0) * CVT_PAD + d], vls[(k0 + 1) * CVT_PAD + d]);
      u32 w1 = pk2(vls[(k0 + 2) * CVT_PAD + d], vls[(k0 + 3) * CVT_PAD + d]);
      u32 w2 = pk2(vls[(k0 + 4) * CVT_PAD + d], vls[(k0 + 5) * CVT_PAD + d]);
      u32 w3 = pk2(vls[(k0 + 6) * CVT_PAD + d], vls[(k0 + 7) * CVT_PAD + d]);
      Vo[(c * 256 + d) * 4 + (o4 & 3)] = make_int4((int)w0, (int)w1, (int)w2, (int)w3);
    }
  }
}

// ================= main kernel: direct bf16 fragment loads, XCD-co-scheduled =================
__global__ __attribute__((amdgpu_waves_per_eu(2, 2))) __launch_bounds__(NTHREADS)
void fa_fwd_pre(const float* __restrict__ Qg, const unsigned short* __restrict__ Kb16,
                const unsigned short* __restrict__ Vt, float* __restrict__ Og, int B) {
  __shared__ int Ssh[BQ * SST];                 // fixed-point partial scores
  __shared__ unsigned short Psh[BQ * PST];      // bf16 probs
  __shared__ float msh[BQ], lsh[BQ], ash[BQ];   // running max / denom / alpha
  __shared__ int fsh[2][4];                     // double-buffered rescale flags

  const int tid = threadIdx.x;
  const int lane = tid & 63;
  const int wave = tid >> 6;         // d-slice owner: cols [wave*128, wave*128+128)
  const int r = lane & 15;
  const int quad = lane >> 4;

  // XCD-co-scheduled mapping: round-robin dispatch (xcd = f%8) puts all 32 CUs of
  // an XCD on ONE batch's q-tiles per round, all streaming the same K/V tile
  // sequence from kt=0 -> per-XCD L2 window stays hot. Heavy-first within round.
  const int f = (int)blockIdx.y * (int)gridDim.x + (int)blockIdx.x;
  int b, qtile;
  if ((B & 7) == 0) {
    int xcd = f & 7;
    int s = f >> 3;                   // per-XCD slot
    b = (s >> 5) * 8 + xcd;          // round * 8 + xcd   (NQT == 32)
    qtile = (NQT - 1) - (s & (NQT - 1));
  } else {
    b = f % B;
    qtile = (int)gridDim.x - 1 - (f / B);
  }
  const int q0 = qtile * BQ;
  const size_t base = (size_t)b * L_SEQ * D_DIM;
  const float* Qb = Qg + base;
  const unsigned short* Kbb = Kb16 + base;
  const unsigned short* Vtb = Vt + (size_t)b * NKT * (size_t)(D_DIM * BK);
  float* Ob = Og + base;

  // ---- Q fragments, bf16, persistent (nt loads: Q touched exactly once) ----
  int4 qf[4][4];
#pragma unroll
  for (int m = 0; m < 4; ++m)
#pragma unroll
    for (int ks = 0; ks < 4; ++ks) {
      const float* src = Qb + (size_t)(q0 + m * 16 + r) * D_DIM + wave * 128 + ks * 32 + quad * 8;
      f32x4 x = ntload4(src);
      f32x4 y = ntload4(src + 4);
      qf[m][ks] = make_int4((int)pk2(x[0], x[1]), (int)pk2(x[2], x[3]),
                            (int)pk2(y[0], y[1]), (int)pk2(y[2], y[3]));
    }

  f32x4 o[4][8];
  const f32x4 fzero = {0.f, 0.f, 0.f, 0.f};
#pragma unroll
  for (int m = 0; m < 4; ++m)
#pragma unroll
    for (int n = 0; n < 8; ++n) o[m][n] = fzero;

  if (tid < BQ) { msh[tid] = -3.0e38f; lsh[tid] = 0.f; }
  if (tid < 8) fsh[tid >> 2][tid & 3] = 0;
  {  // zero score buffer once; thereafter softmax re-zeros its own int4
    int q = tid >> 3, k4 = (tid & 7) * 4;
    *(int4*)&Ssh[q * SST + k4] = make_int4(0, 0, 0, 0);
  }
  __syncthreads();

  const int nkt = q0 / BK + 2;                 // causal tile skip
  const float SC = 0.04508422002778011f;       // log2(e) / sqrt(1024)
  const float SCI = SC / SFIX;

  for (int kt = 0; kt < nkt; ++kt) {
    const int cur = kt & 1;

    // ---- QK^T: direct global bf16 K fragments, reduce via LDS int atomics ----
#pragma unroll
    for (int nb = 0; nb < 2; ++nb) {
      f32x4 sp[4];
#pragma unroll
      for (int m = 0; m < 4; ++m) sp[m] = fzero;
#pragma unroll
      for (int ks = 0; ks < 4; ++ks) {
        int4 kb = *(const int4*)(Kbb + (size_t)(kt * BK + nb * 16 + r) * D_DIM +
                                 wave * 128 + ks * 32 + quad * 8);
#pragma unroll
        for (int m = 0; m < 4; ++m) sp[m] = mfma16(qf[m][ks], kb, sp[m]);
      }
#pragma unroll
      for (int m = 0; m < 4; ++m)
#pragma unroll
        for (int i = 0; i < 4; ++i) {
          int v = __float2int_rn(sp[m][i] * SFIX);
          atomicAdd(&Ssh[(m * 16 + quad * 4 + i) * SST + nb * 16 + r], v);
        }
    }
    __syncthreads();  // (1) S complete; prev-tile P/ash consumers also done

    // ---- online softmax: 8 threads per row; re-zero own S int4 for next tile ----
    {
      int q = tid >> 3, kk = (tid & 7) * 4;
      int4 sv = *(int4*)&Ssh[q * SST + kk];
      *(int4*)&Ssh[q * SST + kk] = make_int4(0, 0, 0, 0);
      int qglob = q0 + q, kglob = kt * BK + kk;
      float e0 = (kglob <= qglob) ? (float)sv.x * SCI : -1e30f;
      float e1 = (kglob + 1 <= qglob) ? (float)sv.y * SCI : -1e30f;
      float e2 = (kglob + 2 <= qglob) ? (float)sv.z * SCI : -1e30f;
      float e3 = (kglob + 3 <= qglob) ? (float)sv.w * SCI : -1e30f;
      float mx = fmaxf(fmaxf(e0, e1), fmaxf(e2, e3));
      mx = fmaxf(mx, __shfl_xor(mx, 1));
      mx = fmaxf(mx, __shfl_xor(mx, 2));
      mx = fmaxf(mx, __shfl_xor(mx, 4));
      float mprev = msh[q], lprev = lsh[q];
      float mnew = fmaxf(mprev, mx);
      float alpha = exp2f(mprev - mnew);
      float p0 = exp2f(e0 - mnew), p1 = exp2f(e1 - mnew);
      float p2 = exp2f(e2 - mnew), p3 = exp2f(e3 - mnew);
      float sum = (p0 + p1) + (p2 + p3);
      sum += __shfl_xor(sum, 1);
      sum += __shfl_xor(sum, 2);
      sum += __shfl_xor(sum, 4);
      *(uint2*)&Psh[q * PST + kk] = make_uint2(pk2(p0, p1), pk2(p2, p3));
      if ((tid & 7) == 0) {
        msh[q] = mnew;
        lsh[q] = lprev * alpha + sum;
        ash[q] = alpha;
        if (alpha != 1.0f) fsh[cur][q >> 4] = 1;  // same-value racy store: fine
      }
      if (tid < 4) fsh[cur ^ 1][tid] = 0;          // reset next tile's flags
    }
    __syncthreads();  // (2) P/alpha/flags ready

    // ---- conditional O rescale + PV with direct global V fragments ----
    {
#pragma unroll
      for (int m = 0; m < 4; ++m) {
        if (fsh[cur][m]) {  // wave-uniform; rarely taken after max saturates
          float a0 = ash[m * 16 + quad * 4 + 0];
          float a1 = ash[m * 16 + quad * 4 + 1];
          float a2 = ash[m * 16 + quad * 4 + 2];
          float a3 = ash[m * 16 + quad * 4 + 3];
#pragma unroll
          for (int n = 0; n < 8; ++n) {
            o[m][n][0] *= a0; o[m][n][1] *= a1; o[m][n][2] *= a2; o[m][n][3] *= a3;
          }
        }
      }
      int4 pf[4];
#pragma unroll
      for (int m = 0; m < 4; ++m)
        pf[m] = *(int4*)&Psh[(m * 16 + r) * PST + quad * 8];
      const unsigned short* Vtt = Vtb + (size_t)kt * (D_DIM * BK);
#pragma unroll
      for (int n = 0; n < 8; ++n) {
        // 16 consecutive 64B d-rows -> each wave load is 1KB fully contiguous
        int4 vb = *(const int4*)(Vtt + (wave * 128 + n * 16 + r) * BK + quad * 8);
#pragma unroll
        for (int m = 0; m < 4; ++m) o[m][n] = mfma16(pf[m], vb, o[m][n]);
      }
    }
  }

  // ---- epilogue: O / l (nt stores: O never re-read) ----
#pragma unroll
  for (int m = 0; m < 4; ++m) {
    float inv0 = 1.0f / lsh[m * 16 + quad * 4 + 0];
    float inv1 = 1.0f / lsh[m * 16 + quad * 4 + 1];
    float inv2 = 1.0f / lsh[m * 16 + quad * 4 + 2];
    float inv3 = 1.0f / lsh[m * 16 + quad * 4 + 3];
#pragma unroll
    for (int n = 0; n < 8; ++n) {
      size_t row = (size_t)q0 + m * 16 + quad * 4;
      size_t col = (size_t)wave * 128 + n * 16 + r;
      __builtin_nontemporal_store(o[m][n][0] * inv0, &Ob[(row + 0) * D_DIM + col]);
      __builtin_nontemporal_store(o[m][n][1] * inv1, &Ob[(row + 1) * D_DIM + col]);
      __builtin_nontemporal_store(o[m][n][2] * inv2, &Ob[(row + 2) * D_DIM + col]);
      __builtin_nontemporal_store(o[m][n][3] * inv3, &Ob[(row + 3) * D_DIM + col]);
    }
  }
}

// ================= fallback: previous verified kernel (used if workspace too small) =================
__global__ __attribute__((amdgpu_waves_per_eu(2, 2))) __launch_bounds__(NTHREADS)
void fa_fwd(const float* __restrict__ Qg, const float* __restrict__ Kg,
            const float* __restrict__ Vg, float* __restrict__ Og) {
  extern __shared__ char smem[];
  unsigned short* Ksh = (unsigned short*)(smem + K_OFF);
  unsigned short* Vtsh = (unsigned short*)(smem + V_OFF);
  int* Ssh = (int*)(smem + S_OFF);
  unsigned short* Psh = (unsigned short*)(smem + P_OFF);
  float* msh = (float*)(smem + M_OFF);
  float* lsh = msh + BQ;
  float* ash = lsh + BQ;
  int* fsh = (int*)(ash + BQ);

  const int tid = threadIdx.x;
  const int lane = tid & 63;
  const int wave = tid >> 6;
  const int r = lane & 15;
  const int quad = lane >> 4;

  const int qtile = (int)gridDim.x - 1 - (int)blockIdx.x;
  const int q0 = qtile * BQ;
  const int b = blockIdx.y;
  const size_t base = (size_t)b * L_SEQ * D_DIM;
  const float* Qb = Qg + base;
  const float* Kb = Kg + base;
  const float* Vb = Vg + base;
  float* Ob = Og + base;

  int4 qf[4][4];
#pragma unroll
  for (int m = 0; m < 4; ++m)
#pragma unroll
    for (int ks = 0; ks < 4; ++ks) {
      const float* src = Qb + (size_t)(q0 + m * 16 + r) * D_DIM + wave * 128 + ks * 32 + quad * 8;
      float4 x = *(const float4*)src;
      float4 y = *(const float4*)(src + 4);
      qf[m][ks] = make_int4((int)pk2(x.x, x.y), (int)pk2(x.z, x.w),
                            (int)pk2(y.x, y.y), (int)pk2(y.z, y.w));
    }

  f32x4 o[4][8];
  const f32x4 fzero = {0.f, 0.f, 0.f, 0.f};
#pragma unroll
  for (int m = 0; m < 4; ++m)
#pragma unroll
    for (int n = 0; n < 8; ++n) o[m][n] = fzero;

  if (tid < BQ) { msh[tid] = -3.0e38f; lsh[tid] = 0.f; }

  const int nkt = q0 / BK + 2;
  const float SC = 0.04508422002778011f;
  const float SCI = SC / SFIX;

  for (int kt = 0; kt < nkt; ++kt) {
    __syncthreads();
    {
      const float* Ks = Kb + (size_t)kt * BK * D_DIM;
#pragma unroll 8
      for (int i = 0; i < 16; ++i) {
        int u = i * NTHREADS + tid;
        int key = u >> 8;
        int c = u & 255;
        float4 v = *(const float4*)(Ks + key * D_DIM + c * 4);
        *(uint2*)&Ksh[key * KST + c * 4] = make_uint2(pk2(v.x, v.y), pk2(v.z, v.w));
      }
      const float* Vs = Vb + (size_t)kt * BK * D_DIM;
#pragma unroll 8
      for (int i = 0; i < 32; ++i) {
        int u = i * NTHREADS + tid;
        int kp = u >> 10;
        int d = u & 1023;
        float a = Vs[kp * 2 * D_DIM + d];
        float c2 = Vs[(kp * 2 + 1) * D_DIM + d];
        *(u32*)&Vtsh[d * VST + kp * 2] = pk2(a, c2);
      }
      int q = tid >> 3, k4 = (tid & 7) * 4;
      *(int4*)&Ssh[q * SST + k4] = make_int4(0, 0, 0, 0);
      if (tid < 4) fsh[tid] = 0;
    }
    __syncthreads();

#pragma unroll
    for (int nb = 0; nb < 2; ++nb) {
      f32x4 sp[4];
#pragma unroll
      for (int m = 0; m < 4; ++m) sp[m] = fzero;
#pragma unroll
      for (int ks = 0; ks < 4; ++ks) {
        int dcol = wave * 128 + ks * 32 + quad * 8;
        int4 kb = *(int4*)&Ksh[(nb * 16 + r) * KST + dcol];
#pragma unroll
        for (int m = 0; m < 4; ++m) sp[m] = mfma16(qf[m][ks], kb, sp[m]);
      }
#pragma unroll
      for (int m = 0; m < 4; ++m)
#pragma unroll
        for (int i = 0; i < 4; ++i) {
          int v = __float2int_rn(sp[m][i] * SFIX);
          atomicAdd(&Ssh[(m * 16 + quad * 4 + i) * SST + nb * 16 + r], v);
        }
    }
    __syncthreads();

    {
      int q = tid >> 3, kk = (tid & 7) * 4;
      int4 sv = *(int4*)&Ssh[q * SST + kk];
      int qglob = q0 + q, kglob = kt * BK + kk;
      float e0 = (kglob <= qglob) ? (float)sv.x * SCI : -1e30f;
      float e1 = (kglob + 1 <= qglob) ? (float)sv.y * SCI : -1e30f;
      float e2 = (kglob + 2 <= qglob) ? (float)sv.z * SCI : -1e30f;
      float e3 = (kglob + 3 <= qglob) ? (float)sv.w * SCI : -1e30f;
      float mx = fmaxf(fmaxf(e0, e1), fmaxf(e2, e3));
      mx = fmaxf(mx, __shfl_xor(mx, 1));
      mx = fmaxf(mx, __shfl_xor(mx, 2));
      mx = fmaxf(mx, __shfl_xor(mx, 4));
      float mprev = msh[q], lprev = lsh[q];
      float mnew = fmaxf(mprev, mx);
      float alpha = exp2f(mprev - mnew);
      float p0 = exp2f(e0 - mnew), p1 = exp2f(e1 - mnew);
      float p2 = exp2f(e2 - mnew), p3 = exp2f(e3 - mnew);
      float sum = (p0 + p1) + (p2 + p3);
      sum += __shfl_xor(sum, 1);
      sum += __shfl_xor(sum, 2);
      sum += __shfl_xor(sum, 4);
      *(uint2*)&Psh[q * PST + kk] = make_uint2(pk2(p0, p1), pk2(p2, p3));
      if ((tid & 7) == 0) {
        msh[q] = mnew;
        lsh[q] = lprev * alpha + sum;
        ash[q] = alpha;
        if (alpha != 1.0f) fsh[q >> 4] = 1;
      }
    }
    __syncthreads();

    {
#pragma unroll
      for (int m = 0; m < 4; ++m) {
        if (fsh[m]) {
          float a0 = ash[m * 16 + quad * 4 + 0];
          float a1 = ash[m * 16 + quad * 4 + 1];
          float a2 = ash[m * 16 + quad * 4 + 2];
          float a3 = ash[m * 16 + quad * 4 + 3];
#pragma unroll
          for (int n = 0; n < 8; ++n) {
            o[m][n][0] *= a0; o[m][n][1] *= a1; o[m][n][2] *= a2; o[m][n][3] *= a3;
          }
        }
      }
      int4 pf[4];
#pragma unroll
      for (int m = 0; m < 4; ++m)
        pf[m] = *(int4*)&Psh[(m * 16 + r) * PST + quad * 8];
#pragma unroll
      for (int n = 0; n < 8; ++n) {
        const unsigned short* vp = &Vtsh[(wave * 128 + n * 16 + r) * VST + quad * 8];
        int4 vb = make_int4(*(const u32*)vp, *(const u32*)(vp + 2),
                            *(const u32*)(vp + 4), *(const u32*)(vp + 6));
#pragma unroll
        for (int m = 0; m < 4; ++m) o[m][n] = mfma16(pf[m], vb, o[m][n]);
      }
    }
  }

#pragma unroll
  for (int m = 0; m < 4; ++m) {
    float inv0 = 1.0f / lsh[m * 16 + quad * 4 + 0];
    float inv1 = 1.0f / lsh[m * 16 + quad * 4 + 1];
    float inv2 = 1.0f / lsh[m * 16 + quad * 4 + 2];
    float inv3 = 1.0f / lsh[m * 16 + quad * 4 + 3];
#pragma unroll
    for (int n = 0; n < 8; ++n) {
      size_t row = (size_t)q0 + m * 16 + quad * 4;
      size_t col = (size_t)wave * 128 + n * 16 + r;
      Ob[(row + 0) * D_DIM + col] = o[m][n][0] * inv0;
      Ob[(row + 1) * D_DIM + col] = o[m][n][1] * inv1;
      Ob[(row + 2) * D_DIM + col] = o[m][n][2] * inv2;
      Ob[(row + 3) * D_DIM + col] = o[m][n][3] * inv3;
    }
  }
}

extern "C" void kernel_launch(void* const* d_in, const int* in_sizes, int n_in,
                              void* d_out, int out_size, void* d_ws, size_t ws_size,
                              hipStream_t stream) {
  const float* Q = (const float*)d_in[0];
  const float* K = (const float*)d_in[1];
  const float* V = (const float*)d_in[2];
  float* O = (float*)d_out;
  int B = in_sizes[0] / (L_SEQ * D_DIM);

  size_t need = (size_t)B * L_SEQ * D_DIM * 2ull * 2ull;  // Kb16 + Vt (bf16)
  if (d_ws != nullptr && ws_size >= need) {
    unsigned short* Kb16 = (unsigned short*)d_ws;
    unsigned short* Vt = Kb16 + (size_t)B * L_SEQ * D_DIM;
    dim3 g1(NKT, B);
    cvt_kv<<<g1, 512, 0, stream>>>(K, V, Kb16, Vt);
    dim3 g2(L_SEQ / BQ, B);
    fa_fwd_pre<<<g2, NTHREADS, 0, stream>>>(Q, Kb16, Vt, O, B);
  } else {
    (void)hipFuncSetAttribute((const void*)fa_fwd, hipFuncAttributeMaxDynamicSharedMemorySize,
                              LDS_TOTAL);
    dim3 grid(L_SEQ / BQ, B);
    fa_fwd<<<grid, NTHREADS, LDS_TOTAL, stream>>>(Q, K, V, O);
  }
}